// Round 7
// baseline (249.349 us; speedup 1.0000x reference)
//
#include <hip/hip_runtime.h>

typedef float floatx4 __attribute__((ext_vector_type(4)));
typedef __bf16 bfx8 __attribute__((ext_vector_type(8)));
typedef __bf16 bfx4 __attribute__((ext_vector_type(4)));

// Problem constants
constexpr int B_ = 2, S_ = 2048, H_ = 2048, NH_ = 16, NKV_ = 4, HD_ = 64;
constexpr int M_ = B_ * S_;               // 4096 rows
constexpr int NQKV_ = NH_ * HD_ + 2 * NKV_ * HD_; // 1536
constexpr int HQ_ = NH_ * HD_;            // 1024
// Padded pitches (break 4KB/2KB row strides -> channel aliasing; round-4 win)
constexpr int XP_ = 2056;  // xbf / wqkvT pitch
constexpr int AP_ = 1032;  // attn-out / woT pitch
constexpr int VP_ = 2056;  // V-transposed pitch

#define GLB(p) ((const __attribute__((address_space(1))) void*)(p))
#define LDS(p) ((__attribute__((address_space(3))) void*)(p))

// ---------------- fp32 -> bf16 cast into padded-pitch buffer ----------------
__global__ __launch_bounds__(256) void cast_f32_bf16_pad(const float* __restrict__ src,
                                                         __bf16* __restrict__ dst) {
  int row = blockIdx.x;
  const float4* s = (const float4*)(src + (size_t)row * H_);
  __bf16* d = dst + (size_t)row * XP_;
#pragma unroll
  for (int i = 0; i < 2; i++) {
    int c = i * 256 + threadIdx.x;
    float4 v = s[c];
    bfx4 o;
    o[0] = (__bf16)v.x; o[1] = (__bf16)v.y; o[2] = (__bf16)v.z; o[3] = (__bf16)v.w;
    *(bfx4*)(d + c * 4) = o;
  }
}

// ---------------- transpose + cast: dst[n+off][k] = src[k][n] ----------------
__global__ __launch_bounds__(256) void transpose_cast(const float* __restrict__ src,
                                                      __bf16* __restrict__ dst,
                                                      int K, int N, int dstOff, int dstPitch) {
  __shared__ float tile[32][33];
  int n0 = blockIdx.x * 32, k0 = blockIdx.y * 32;
  int tx = threadIdx.x, ty = threadIdx.y; // block (32,8)
#pragma unroll
  for (int r = 0; r < 32; r += 8)
    tile[ty + r][tx] = src[(size_t)(k0 + ty + r) * N + n0 + tx];
  __syncthreads();
#pragma unroll
  for (int r = 0; r < 32; r += 8)
    dst[(size_t)(n0 + ty + r + dstOff) * dstPitch + k0 + tx] = (__bf16)tile[tx][ty + r];
}

// ---------------- bf16 MFMA GEMM, 64x128 tile, global_load_lds staging ------------
// A: MxK (lda), Bt: NxK (ldb), C: MxN fp32 (ldc). BK=64. 4 waves side-by-side in N;
// wave computes 64x32 (acc 4x2). Round-6 lesson: 128x128 tiles gave only 384 blocks
// (1.5/CU) for N=1536 -> occupancy 14%, latency-starved. 64-row tiles double the grid:
// QKV 768 blocks = 3.0/CU, out-proj 1024 = 4.0/CU, both exactly balanced.
// LDS unpadded (DMA dest = uniform base + lane*16); XOR swizzle on the SOURCE address:
// LDS group g at row r holds logical group g^(r&7) -> conflict-free frag reads (R6: 0 conflicts).
__global__ __launch_bounds__(256) void gemm_bf16_f32(const __bf16* __restrict__ A,
                                                     const __bf16* __restrict__ Bt,
                                                     float* __restrict__ C,
                                                     int M, int N, int K,
                                                     int lda, int ldb, int ldc) {
  __shared__ __align__(16) __bf16 As[64 * 64];
  __shared__ __align__(16) __bf16 Bs[128 * 64];
  int wid = threadIdx.x >> 6, lane = threadIdx.x & 63;
  int l15 = lane & 15, quad = lane >> 4;
  int wn = wid * 32;
  int m0 = blockIdx.y * 64, n0 = blockIdx.x * 128;
  int srow_off = lane >> 3;   // 0..7
  int gphys = lane & 7;       // physical 16B group
  floatx4 acc[4][2] = {};
  for (int kb = 0; kb < K; kb += 64) {
    // A: 64 rows, 8 DMA instrs total -> 2 per wave
#pragma unroll
    for (int j = 0; j < 2; j++) {
      int rbase = wid * 16 + j * 8;
      int row = rbase + srow_off;
      int glog = gphys ^ (row & 7);
      const __bf16* ga = &A[(size_t)(m0 + row) * lda + kb + glog * 8];
      __builtin_amdgcn_global_load_lds(GLB(ga), LDS(&As[rbase * 64]), 16, 0, 0);
    }
    // B: 128 rows, 16 DMA instrs total -> 4 per wave
#pragma unroll
    for (int j = 0; j < 4; j++) {
      int rbase = wid * 32 + j * 8;
      int row = rbase + srow_off;
      int glog = gphys ^ (row & 7);
      const __bf16* gb = &Bt[(size_t)(n0 + row) * ldb + kb + glog * 8];
      __builtin_amdgcn_global_load_lds(GLB(gb), LDS(&Bs[rbase * 64]), 16, 0, 0);
    }
    __syncthreads();
#pragma unroll
    for (int kk = 0; kk < 64; kk += 32) {
      int cgq = (kk >> 3) + quad; // logical 16B-group of this quad's fragment
      bfx8 af[4], bfr[2];
#pragma unroll
      for (int mi = 0; mi < 4; mi++) {
        int row = mi * 16 + l15;
        af[mi] = *(const bfx8*)&As[row * 64 + ((cgq ^ (row & 7)) * 8)];
      }
#pragma unroll
      for (int ni = 0; ni < 2; ni++) {
        int row = wn + ni * 16 + l15;
        bfr[ni] = *(const bfx8*)&Bs[row * 64 + ((cgq ^ (row & 7)) * 8)];
      }
#pragma unroll
      for (int mi = 0; mi < 4; mi++)
#pragma unroll
        for (int ni = 0; ni < 2; ni++)
          acc[mi][ni] = __builtin_amdgcn_mfma_f32_16x16x32_bf16(af[mi], bfr[ni], acc[mi][ni], 0, 0, 0);
    }
    __syncthreads();
  }
#pragma unroll
  for (int mi = 0; mi < 4; mi++)
#pragma unroll
    for (int ni = 0; ni < 2; ni++) {
      int row = m0 + mi * 16 + quad * 4;
      int coln = n0 + wn + ni * 16 + l15;
#pragma unroll
      for (int r = 0; r < 4; r++)
        C[(size_t)(row + r) * ldc + coln] = acc[mi][ni][r];
    }
}

// ---------------- RMSNorm + RoPE on q/k, cast+layout for attention ----------------
__global__ __launch_bounds__(256) void norm_rope_kernel(const float* __restrict__ qkv,
                                                        const float* __restrict__ cosT,
                                                        const float* __restrict__ sinT,
                                                        const float* __restrict__ qw,
                                                        const float* __restrict__ kw,
                                                        __bf16* __restrict__ Qo,
                                                        __bf16* __restrict__ Ko,
                                                        __bf16* __restrict__ VTo) {
  int s = blockIdx.x, b = blockIdx.y;
  int wid = threadIdx.x >> 6, lane = threadIdx.x & 63;
  const float* rowp = qkv + (size_t)(b * S_ + s) * NQKV_;
  float c = cosT[s * HD_ + lane];
  float sn = sinT[s * HD_ + lane];
#pragma unroll
  for (int it = 0; it < 5; it++) {
    int hh = it * 4 + wid; // 0..15 q heads, 16..19 k heads
    float v = rowp[hh * 64 + lane];
    float ss = v * v;
#pragma unroll
    for (int off = 1; off < 64; off <<= 1) ss += __shfl_xor(ss, off);
    float rs = rsqrtf(ss * (1.0f / 64.0f) + 1e-6f);
    const float* w = (hh < 16) ? qw : kw;
    float nv = v * rs * w[lane];
    float other = __shfl_xor(nv, 32);
    float rot = (lane < 32) ? -other : other; // rotate_half
    float outv = nv * c + rot * sn;
    if (hh < 16)
      Qo[(((size_t)b * NH_ + hh) * S_ + s) * HD_ + lane] = (__bf16)outv;
    else
      Ko[(((size_t)b * NKV_ + (hh - 16)) * S_ + s) * HD_ + lane] = (__bf16)outv;
  }
  {
    float v = rowp[(20 + wid) * 64 + lane];
    VTo[(((size_t)b * NKV_ + wid) * HD_ + lane) * VP_ + s] = (__bf16)v;
  }
}

// ---------------- flash attention (causal, GQA), block-cooperative LDS staging ----------
__global__ __launch_bounds__(256, 4) void attn_kernel(const __bf16* __restrict__ Q,
                                                      const __bf16* __restrict__ Kc,
                                                      const __bf16* __restrict__ VT,
                                                      __bf16* __restrict__ Ob) {
  int px = blockIdx.x, h = blockIdx.y, b = blockIdx.z;
  int u = (px + 2 * (h & 7)) & 31;
  int qt = (((h >> 3) ^ b) & 1) ? (31 - u) : u;
  int wid = threadIdx.x >> 6, lane = threadIdx.x & 63;
  int l15 = lane & 15, quad = lane >> 4;
  int q0 = qt * 64 + wid * 16;
  int kvh = h >> 2; // N_REP = 4
  const __bf16* Qh = Q + (((size_t)b * NH_ + h) * S_ + q0) * HD_;
  const __bf16* Kh = Kc + ((size_t)b * NKV_ + kvh) * S_ * HD_;
  const __bf16* Vh = VT + ((size_t)b * NKV_ + kvh) * (size_t)HD_ * VP_;
  __shared__ __align__(16) __bf16 Ks[64][72]; // [kv][hd]
  __shared__ __align__(16) __bf16 Vs[64][72]; // [hd][kv]
  __shared__ __align__(16) __bf16 Pst[4][16][72];
  __bf16 (*P)[72] = Pst[wid];

  int srow = threadIdx.x >> 3;         // 0..31
  int scol = (threadIdx.x & 7) * 8;    // element offset 0..56

  bfx8 qf0, qf1;
  {
    const __bf16* qp = Qh + l15 * HD_ + quad * 8;
    qf0 = *(const bfx8*)qp;
    qf1 = *(const bfx8*)(qp + 32);
  }
  floatx4 oacc[4] = {};
  float ps = 0.f;
  int ntiles = qt + 1; // causal, block-uniform
  bfx8 kpre0, kpre1, vpre0, vpre1;
  kpre0 = *(const bfx8*)&Kh[(size_t)srow * HD_ + scol];
  kpre1 = *(const bfx8*)&Kh[(size_t)(srow + 32) * HD_ + scol];
  vpre0 = *(const bfx8*)&Vh[(size_t)srow * VP_ + scol];
  vpre1 = *(const bfx8*)&Vh[(size_t)(srow + 32) * VP_ + scol];
  for (int kt = 0; kt < ntiles; kt++) {
    int kv0 = kt * 64;
    int dq = q0 - kv0;
    __syncthreads();
    *(bfx8*)&Ks[srow][scol] = kpre0;
    *(bfx8*)&Ks[srow + 32][scol] = kpre1;
    *(bfx8*)&Vs[srow][scol] = vpre0;
    *(bfx8*)&Vs[srow + 32][scol] = vpre1;
    __syncthreads();
    if (kt + 1 < ntiles) {
      int kn = kv0 + 64;
      kpre0 = *(const bfx8*)&Kh[(size_t)(kn + srow) * HD_ + scol];
      kpre1 = *(const bfx8*)&Kh[(size_t)(kn + srow + 32) * HD_ + scol];
      vpre0 = *(const bfx8*)&Vh[(size_t)srow * VP_ + kn + scol];
      vpre1 = *(const bfx8*)&Vh[(size_t)(srow + 32) * VP_ + kn + scol];
    }
    floatx4 sf[4];
#pragma unroll
    for (int nt = 0; nt < 4; nt++) {
      bfx8 kf0 = *(const bfx8*)&Ks[nt * 16 + l15][quad * 8];
      bfx8 kf1 = *(const bfx8*)&Ks[nt * 16 + l15][32 + quad * 8];
      floatx4 z = {0.f, 0.f, 0.f, 0.f};
      z = __builtin_amdgcn_mfma_f32_16x16x32_bf16(kf0, qf0, z, 0, 0, 0);
      sf[nt] = __builtin_amdgcn_mfma_f32_16x16x32_bf16(kf1, qf1, z, 0, 0, 0);
    }
#pragma unroll
    for (int nt = 0; nt < 4; nt++) {
      bfx4 pk;
#pragma unroll
      for (int r = 0; r < 4; r++) {
        int kvrel = nt * 16 + quad * 4 + r;
        float p = __expf(sf[nt][r] * 0.125f);
        p = (kvrel - l15 > dq) ? 0.f : p;
        ps += p;
        pk[r] = (__bf16)p;
      }
      *(bfx4*)&P[l15][nt * 16 + quad * 4] = pk;
    }
    bfx8 pa0 = *(const bfx8*)&P[l15][quad * 8];
    bfx8 pa1 = *(const bfx8*)&P[l15][32 + quad * 8];
#pragma unroll
    for (int ot = 0; ot < 4; ot++) {
      bfx8 vf0 = *(const bfx8*)&Vs[ot * 16 + l15][quad * 8];
      bfx8 vf1 = *(const bfx8*)&Vs[ot * 16 + l15][32 + quad * 8];
      oacc[ot] = __builtin_amdgcn_mfma_f32_16x16x32_bf16(pa0, vf0, oacc[ot], 0, 0, 0);
      oacc[ot] = __builtin_amdgcn_mfma_f32_16x16x32_bf16(pa1, vf1, oacc[ot], 0, 0, 0);
    }
  }
  ps += __shfl_xor(ps, 16);
  ps += __shfl_xor(ps, 32);
  float rl[4];
#pragma unroll
  for (int r = 0; r < 4; r++) rl[r] = 1.0f / __shfl(ps, quad * 4 + r);
#pragma unroll
  for (int ot = 0; ot < 4; ot++)
#pragma unroll
    for (int r = 0; r < 4; r++) {
      float val = oacc[ot][r] * rl[r];
      Ob[((size_t)b * S_ + q0 + quad * 4 + r) * AP_ + h * HD_ + ot * 16 + l15] = (__bf16)val;
    }
}

extern "C" void kernel_launch(void* const* d_in, const int* in_sizes, int n_in,
                              void* d_out, int out_size, void* d_ws, size_t ws_size,
                              hipStream_t stream) {
  const float* x   = (const float*)d_in[0];
  const float* cosT = (const float*)d_in[1];
  const float* sinT = (const float*)d_in[2];
  const float* wq  = (const float*)d_in[3];
  const float* wk  = (const float*)d_in[4];
  const float* wv  = (const float*)d_in[5];
  const float* wo  = (const float*)d_in[6];
  const float* qw  = (const float*)d_in[7];
  const float* kw  = (const float*)d_in[8];
  float* out = (float*)d_out;

  char* w = (char*)d_ws;
  __bf16* xbf   = (__bf16*)(w);                        // 4096*2056*2 = 16,842,752
  __bf16* wqkvT = (__bf16*)(w + 16842752);             // 1536*2056*2 =  6,316,032
  __bf16* woT   = (__bf16*)(w + 23158784);             // 2048*1032*2 =  4,227,072
  float*  qkv   = (float*) (w + 27385856);             // 4096*1536*4 = 25,165,824
  __bf16* attnO = (__bf16*)(w + 27385856);             // aliases qkv (qkv dead after norm_rope)
  __bf16* Qb    = (__bf16*)(w + 52551680);             //  8,388,608
  __bf16* Kb    = (__bf16*)(w + 60940288);             //  2,097,152
  __bf16* VTb   = (__bf16*)(w + 63037440);             // 2*4*64*2056*2 = 2,105,344 (end 65,142,784)

  cast_f32_bf16_pad<<<M_, 256, 0, stream>>>(x, xbf);
  dim3 tb(32, 8);
  transpose_cast<<<dim3(1024 / 32, 2048 / 32), tb, 0, stream>>>(wq, wqkvT, 2048, 1024, 0,    XP_);
  transpose_cast<<<dim3(256 / 32, 2048 / 32),  tb, 0, stream>>>(wk, wqkvT, 2048, 256,  1024, XP_);
  transpose_cast<<<dim3(256 / 32, 2048 / 32),  tb, 0, stream>>>(wv, wqkvT, 2048, 256,  1280, XP_);
  transpose_cast<<<dim3(2048 / 32, 1024 / 32), tb, 0, stream>>>(wo, woT,   1024, 2048, 0,    AP_);
  gemm_bf16_f32<<<dim3(NQKV_ / 128, M_ / 64), 256, 0, stream>>>(xbf, wqkvT, qkv, M_, NQKV_, H_, XP_, XP_, NQKV_);
  norm_rope_kernel<<<dim3(S_, B_), 256, 0, stream>>>(qkv, cosT, sinT, qw, kw, Qb, Kb, VTb);
  attn_kernel<<<dim3(32, NH_, B_), 256, 0, stream>>>(Qb, Kb, VTb, attnO);
  gemm_bf16_f32<<<dim3(H_ / 128, M_ / 64), 256, 0, stream>>>(attnO, woT, out, M_, H_, HQ_, AP_, AP_, H_);
}